// Round 1
// 4498.351 us; speedup vs baseline: 2.0549x; 2.0549x over previous
//
#include <hip/hip_runtime.h>

typedef unsigned short u16;
typedef __bf16 bf16x8 __attribute__((ext_vector_type(8)));
typedef float f32x4 __attribute__((ext_vector_type(4)));

#define TB 4
#define TT 1024
#define TD 768
#define TH 12
#define THD 64
#define TV 50304

__device__ __forceinline__ float b2f(u16 u) {
    union { unsigned int i; float f; } v; v.i = ((unsigned int)u) << 16; return v.f;
}
__device__ __forceinline__ u16 f2b(float f) {
    union { float f; unsigned int i; } v; v.f = f;
    unsigned int r = v.i + 0x7FFFu + ((v.i >> 16) & 1u);
    return (u16)(r >> 16);
}

// ---------------- GEMM: C[M,N] = A[M,K](bf16) * W^T(fp32, cvt) (+bias fp32) ----
// B_KN=false: W is [N][K] (K contiguous).  B_KN=true: W is [K][N] (N contiguous).
// OUT_RES=0: write bf16 to Cb.  OUT_RES=1: Cf[m*N+n] += acc + bias (fp32 residual).
#define BM 128
#define BN 128
#define BK 32
#define LSTR 40  // BK + 8 pad, elements

template<bool B_KN, int OUT_RES>
__global__ __launch_bounds__(256) void gemm_k(
    const u16* __restrict__ A, const float* __restrict__ W,
    const float* __restrict__ bias, u16* __restrict__ Cb, float* __restrict__ Cf,
    int M, int N, int K)
{
    __shared__ u16 Als[BM * LSTR];
    __shared__ u16 Bls[BN * LSTR];
    const int tid = threadIdx.x;
    const int n0 = blockIdx.x * BN;
    const int m0 = blockIdx.y * BM;
    const int wave = tid >> 6;
    const int lane = tid & 63;
    const int wm = (wave >> 1) * 64;
    const int wn = (wave & 1) * 64;
    const int q = lane >> 4;
    const int r = lane & 15;

    f32x4 acc[4][4];
#pragma unroll
    for (int i = 0; i < 4; ++i)
#pragma unroll
        for (int j = 0; j < 4; ++j) acc[i][j] = (f32x4){0.f, 0.f, 0.f, 0.f};

    for (int k0 = 0; k0 < K; k0 += BK) {
        __syncthreads();
        // stage A tile [BM][BK] (already bf16)
#pragma unroll
        for (int c = 0; c < 2; ++c) {
            int chunk = tid + c * 256;
            int row = chunk >> 2;
            int col = (chunk & 3) * 8;
            *(uint4*)(&Als[row * LSTR + col]) =
                *(const uint4*)(A + (size_t)(m0 + row) * K + k0 + col);
        }
        if (!B_KN) {
#pragma unroll
            for (int c = 0; c < 2; ++c) {
                int chunk = tid + c * 256;
                int row = chunk >> 2;
                int col = (chunk & 3) * 8;
                const float* src = W + (size_t)(n0 + row) * K + k0 + col;
                float4 v0 = *(const float4*)src;
                float4 v1 = *(const float4*)(src + 4);
                union { u16 s[8]; uint4 v; } pk;
                pk.s[0] = f2b(v0.x); pk.s[1] = f2b(v0.y);
                pk.s[2] = f2b(v0.z); pk.s[3] = f2b(v0.w);
                pk.s[4] = f2b(v1.x); pk.s[5] = f2b(v1.y);
                pk.s[6] = f2b(v1.z); pk.s[7] = f2b(v1.w);
                *(uint4*)(&Bls[row * LSTR + col]) = pk.v;
            }
        } else {
#pragma unroll
            for (int c = 0; c < 2; ++c) {
                int chunk = tid + c * 256;
                int krow = chunk >> 4;
                int ncol = (chunk & 15) * 8;
                const float* src = W + (size_t)(k0 + krow) * N + n0 + ncol;
                float4 v0 = *(const float4*)src;
                float4 v1 = *(const float4*)(src + 4);
                u16 s[8];
                s[0] = f2b(v0.x); s[1] = f2b(v0.y); s[2] = f2b(v0.z); s[3] = f2b(v0.w);
                s[4] = f2b(v1.x); s[5] = f2b(v1.y); s[6] = f2b(v1.z); s[7] = f2b(v1.w);
#pragma unroll
                for (int j = 0; j < 8; ++j)
                    Bls[(ncol + j) * LSTR + krow] = s[j];
            }
        }
        __syncthreads();
        bf16x8 af[4], bfv[4];
#pragma unroll
        for (int i = 0; i < 4; ++i)
            af[i] = *(const bf16x8*)(&Als[(wm + i * 16 + r) * LSTR + q * 8]);
#pragma unroll
        for (int j = 0; j < 4; ++j)
            bfv[j] = *(const bf16x8*)(&Bls[(wn + j * 16 + r) * LSTR + q * 8]);
#pragma unroll
        for (int i = 0; i < 4; ++i)
#pragma unroll
            for (int j = 0; j < 4; ++j)
                acc[i][j] = __builtin_amdgcn_mfma_f32_16x16x32_bf16(
                    af[i], bfv[j], acc[i][j], 0, 0, 0);
    }
#pragma unroll
    for (int i = 0; i < 4; ++i) {
        int mrow = m0 + wm + i * 16 + q * 4;
#pragma unroll
        for (int j = 0; j < 4; ++j) {
            int ncol = n0 + wn + j * 16 + r;
            float bval = bias ? bias[ncol] : 0.f;
#pragma unroll
            for (int p = 0; p < 4; ++p) {
                float outv = acc[i][j][p] + bval;
                if (OUT_RES) {
                    Cf[(size_t)(mrow + p) * N + ncol] += outv;
                } else {
                    Cb[(size_t)(mrow + p) * N + ncol] = f2b(outv);
                }
            }
        }
    }
}

// ---------------- Flash attention (MFMA): 64-query tile, 4 waves ----------------
// Block = 256 thr (4 waves), wave w owns queries q0+w*16 .. +15.
// KV tiles of 64 staged in LDS; QK^T and PV via mfma_f32_16x16x32_bf16.
// Operand conventions identical to gemm_k above (HW-verified there):
//   A[m][k]: m=lane&15, k=(lane>>4)*8+j     B[k][n]: n=lane&15, k=(lane>>4)*8+j
//   C[m][n]: n=lane&15, m=(lane>>4)*4+p
#define ASTR 72  // 64 + 8 pad, elements

__global__ __launch_bounds__(256) void fattn_k(const u16* __restrict__ qkv,
                                               u16* __restrict__ y)
{
    const int tid = threadIdx.x;
    const int wave = tid >> 6;
    const int lane = tid & 63;
    const int r = lane & 15;
    const int qh = lane >> 4;
    const int bh = blockIdx.x;          // b*12 + h
    const int h = bh % 12;
    const int b = bh / 12;
    const int qt = 15 - (int)blockIdx.y;  // longest tiles scheduled first
    const int q0 = qt * 64;
    const size_t rstride = 3 * TD;

    __shared__ __align__(16) u16 Kls[64 * ASTR];
    __shared__ __align__(16) u16 Vls[64 * ASTR];
    __shared__ __align__(16) u16 Pls[4][16 * ASTR];

    const u16* base = qkv + (size_t)(b * TT) * rstride + h * 64;

    // Q A-fragments (held in regs for whole kernel): query = q0+wave*16+r
    bf16x8 qf[2];
    {
        const u16* qrow = base + (size_t)(q0 + wave * 16 + r) * rstride;
        qf[0] = *(const bf16x8*)(qrow + qh * 8);
        qf[1] = *(const bf16x8*)(qrow + 32 + qh * 8);
    }

    f32x4 o[4];          // O[q = qh*4+p][d = db*16+r]
    float m[4], l[4];    // per-row stats, row = qh*4+p (replicated over r lanes)
#pragma unroll
    for (int db = 0; db < 4; ++db) o[db] = (f32x4){0.f, 0.f, 0.f, 0.f};
#pragma unroll
    for (int p = 0; p < 4; ++p) { m[p] = -1e30f; l[p] = 0.f; }

    for (int kt = 0; kt <= qt; ++kt) {
        const int kv0 = kt * 64;
        __syncthreads();  // prev tile's compute done before restage
#pragma unroll
        for (int i = 0; i < 2; ++i) {
            int c = tid + i * 256;
            int row = c >> 3;
            int col = (c & 7) * 8;
            const u16* ksrc = base + TD + (size_t)(kv0 + row) * rstride + col;
            *(uint4*)(&Kls[row * ASTR + col]) = *(const uint4*)ksrc;
            *(uint4*)(&Vls[row * ASTR + col]) = *(const uint4*)(ksrc + TD);
        }
        __syncthreads();

        // S = Q K^T, 4 key blocks of 16
        float sv[4][4];  // [kb][p]
#pragma unroll
        for (int kb = 0; kb < 4; ++kb) {
            f32x4 s4 = (f32x4){0.f, 0.f, 0.f, 0.f};
            bf16x8 kf0 = *(const bf16x8*)(&Kls[(kb * 16 + r) * ASTR + qh * 8]);
            bf16x8 kf1 = *(const bf16x8*)(&Kls[(kb * 16 + r) * ASTR + 32 + qh * 8]);
            s4 = __builtin_amdgcn_mfma_f32_16x16x32_bf16(qf[0], kf0, s4, 0, 0, 0);
            s4 = __builtin_amdgcn_mfma_f32_16x16x32_bf16(qf[1], kf1, s4, 0, 0, 0);
            int key = kv0 + kb * 16 + r;
#pragma unroll
            for (int p = 0; p < 4; ++p) {
                int qg = q0 + wave * 16 + qh * 4 + p;
                sv[kb][p] = (key <= qg) ? s4[p] * 0.125f : -1e30f;
            }
        }
        // per-row tile max (reduce over r lanes: offsets 1..8 stay in qh-group)
        float pm[4];
#pragma unroll
        for (int p = 0; p < 4; ++p)
            pm[p] = fmaxf(fmaxf(sv[0][p], sv[1][p]), fmaxf(sv[2][p], sv[3][p]));
#pragma unroll
        for (int off = 1; off < 16; off <<= 1)
#pragma unroll
            for (int p = 0; p < 4; ++p)
                pm[p] = fmaxf(pm[p], __shfl_xor(pm[p], off, 64));
        float crr[4];
#pragma unroll
        for (int p = 0; p < 4; ++p) {
            float mn = fmaxf(m[p], pm[p]);
            crr[p] = __expf(m[p] - mn);
            m[p] = mn;
        }
        float rs[4] = {0.f, 0.f, 0.f, 0.f};
#pragma unroll
        for (int kb = 0; kb < 4; ++kb)
#pragma unroll
            for (int p = 0; p < 4; ++p) {
                float pv = __expf(sv[kb][p] - m[p]);
                sv[kb][p] = pv;
                rs[p] += pv;
            }
#pragma unroll
        for (int off = 1; off < 16; off <<= 1)
#pragma unroll
            for (int p = 0; p < 4; ++p) rs[p] += __shfl_xor(rs[p], off, 64);
#pragma unroll
        for (int p = 0; p < 4; ++p) l[p] = l[p] * crr[p] + rs[p];
#pragma unroll
        for (int db = 0; db < 4; ++db)
#pragma unroll
            for (int p = 0; p < 4; ++p) o[db][p] *= crr[p];

        // P: C-layout -> per-wave LDS slab -> A-layout fragments
#pragma unroll
        for (int kb = 0; kb < 4; ++kb)
#pragma unroll
            for (int p = 0; p < 4; ++p)
                Pls[wave][(qh * 4 + p) * ASTR + kb * 16 + r] = f2b(sv[kb][p]);
        bf16x8 pf0 = *(const bf16x8*)(&Pls[wave][r * ASTR + qh * 8]);
        bf16x8 pf1 = *(const bf16x8*)(&Pls[wave][r * ASTR + 32 + qh * 8]);

        // O += P V : B-frag gathered from row-major V tile
#pragma unroll
        for (int db = 0; db < 4; ++db) {
#pragma unroll
            for (int c = 0; c < 2; ++c) {
                bf16x8 vf;
#pragma unroll
                for (int j = 0; j < 8; ++j)
                    ((u16*)&vf)[j] = Vls[(c * 32 + qh * 8 + j) * ASTR + db * 16 + r];
                o[db] = __builtin_amdgcn_mfma_f32_16x16x32_bf16(
                    (c == 0) ? pf0 : pf1, vf, o[db], 0, 0, 0);
            }
        }
    }
#pragma unroll
    for (int p = 0; p < 4; ++p) {
        int qg = q0 + wave * 16 + qh * 4 + p;
        float inv = 1.f / l[p];
#pragma unroll
        for (int db = 0; db < 4; ++db)
            y[(size_t)(b * TT + qg) * TD + h * 64 + db * 16 + r] =
                f2b(o[db][p] * inv);
    }
}

// ---------------- LayerNorm: fp32 in, bf16 out ----------------
__global__ __launch_bounds__(256) void ln_k(const float* __restrict__ x,
    size_t in_stride, const float* __restrict__ w, const float* __restrict__ b,
    u16* __restrict__ out)
{
    const int row = blockIdx.x;
    const int tid = threadIdx.x;
    const float* xr = x + (size_t)row * in_stride;
    float v[3];
    float s = 0.f, ss = 0.f;
#pragma unroll
    for (int i = 0; i < 3; ++i) {
        v[i] = xr[tid + i * 256];
        s += v[i]; ss += v[i] * v[i];
    }
#pragma unroll
    for (int off = 32; off; off >>= 1) {
        s += __shfl_xor(s, off, 64);
        ss += __shfl_xor(ss, off, 64);
    }
    __shared__ float red[8];
    __shared__ float stats[2];
    if ((tid & 63) == 0) { red[tid >> 6] = s; red[4 + (tid >> 6)] = ss; }
    __syncthreads();
    if (tid == 0) {
        float S = red[0] + red[1] + red[2] + red[3];
        float SS = red[4] + red[5] + red[6] + red[7];
        float mu = S * (1.f / 768.f);
        float var = SS * (1.f / 768.f) - mu * mu;
        stats[0] = mu;
        stats[1] = rsqrtf(var + 1e-5f);
    }
    __syncthreads();
    float mu = stats[0], rstd = stats[1];
#pragma unroll
    for (int i = 0; i < 3; ++i) {
        int d = tid + i * 256;
        out[(size_t)row * TD + d] = f2b((v[i] - mu) * rstd * w[d] + b[d]);
    }
}

// ---------------- Embedding (fp32 tables -> fp32 residual) ----------------
__global__ __launch_bounds__(256) void embed_k(const int* __restrict__ idx,
    const float* __restrict__ wte, const float* __restrict__ wpe,
    float* __restrict__ x)
{
    const int row = blockIdx.x;  // b*T + t
    const int t = row & (TT - 1);
    const int tid = threadIdx.x;
    const int tok = idx[row];
#pragma unroll
    for (int i = 0; i < 3; ++i) {
        int d = tid + i * 256;
        x[(size_t)row * TD + d] =
            wte[(size_t)tok * TD + d] + wpe[(size_t)t * TD + d];
    }
}

// ---------------- SwiGLU elementwise (bf16 in/out) ----------------
__global__ __launch_bounds__(256) void swiglu_k(const u16* __restrict__ a,
    const u16* __restrict__ bv, u16* __restrict__ out)
{
    size_t i = (size_t)blockIdx.x * 256 + threadIdx.x;
    float av = b2f(a[i]);
    float g = av / (1.f + __expf(-av));
    out[i] = f2b(g * b2f(bv[i]));
}

// ---------------- lm_head: M=4 skinny GEMM, one wave per output col --------
__global__ __launch_bounds__(256) void lmhead_k(const u16* __restrict__ xf,
    const float* __restrict__ w, float* __restrict__ out)
{
    __shared__ float xs[4 * TD];
    const int tid = threadIdx.x;
    for (int i = tid; i < 4 * TD; i += 256) xs[i] = b2f(xf[i]);
    __syncthreads();
    const int wave = tid >> 6, lane = tid & 63;
    const int n = blockIdx.x * 4 + wave;
    float a0 = 0.f, a1 = 0.f, a2 = 0.f, a3 = 0.f;
    const float* wr = w + (size_t)n * TD;
#pragma unroll
    for (int it = 0; it < 3; ++it) {
        int k = it * 256 + lane * 4;
        float4 wv = *(const float4*)(wr + k);
        const float* wsp = (const float*)&wv;
#pragma unroll
        for (int j = 0; j < 4; ++j) {
            float wf = wsp[j];
            a0 += wf * xs[0 * TD + k + j];
            a1 += wf * xs[1 * TD + k + j];
            a2 += wf * xs[2 * TD + k + j];
            a3 += wf * xs[3 * TD + k + j];
        }
    }
#pragma unroll
    for (int off = 32; off; off >>= 1) {
        a0 += __shfl_xor(a0, off, 64);
        a1 += __shfl_xor(a1, off, 64);
        a2 += __shfl_xor(a2, off, 64);
        a3 += __shfl_xor(a3, off, 64);
    }
    if (lane == 0) {
        out[0 * TV + n] = a0;
        out[1 * TV + n] = a1;
        out[2 * TV + n] = a2;
        out[3 * TV + n] = a3;
    }
}

extern "C" void kernel_launch(void* const* d_in, const int* in_sizes, int n_in,
                              void* d_out, int out_size, void* d_ws, size_t ws_size,
                              hipStream_t stream)
{
    const int* idx = (const int*)d_in[0];
    const float* wte = (const float*)d_in[1];
    const float* wpe = (const float*)d_in[2];
    const float* ln1_w = (const float*)d_in[3];
    const float* ln1_b = (const float*)d_in[4];
    const float* c_attn_w = (const float*)d_in[5];
    const float* c_attn_b = (const float*)d_in[6];
    const float* c_proj_w = (const float*)d_in[7];
    const float* c_proj_b = (const float*)d_in[8];
    const float* ln2_w = (const float*)d_in[9];
    const float* ln2_b = (const float*)d_in[10];
    const float* c_fc_w = (const float*)d_in[11];
    const float* c_fc_b = (const float*)d_in[12];
    const float* sw_W = (const float*)d_in[13];
    const float* sw_V = (const float*)d_in[14];
    const float* sw_b = (const float*)d_in[15];
    const float* sw_c = (const float*)d_in[16];
    const float* mlp_proj_w = (const float*)d_in[17];
    const float* mlp_proj_b = (const float*)d_in[18];
    const float* lnf_w = (const float*)d_in[19];
    const float* lnf_b = (const float*)d_in[20];
    const float* lm_head_w = (const float*)d_in[21];
    float* out = (float*)d_out;

    const int M = TB * TT;  // 4096 rows
    char* ws = (char*)d_ws;
    float* x  = (float*)ws;  ws += (size_t)M * TD * 4;        // fp32 residual
    u16* xn   = (u16*)ws;    ws += (size_t)M * TD * 2;        // ln out (bf16)
    u16* qkvb = (u16*)ws;    ws += (size_t)M * 3 * TD * 2;    // qkv (bf16)
    u16* yb   = (u16*)ws;    ws += (size_t)M * TD * 2;        // attn out (bf16)
    u16* hb   = (u16*)ws;    ws += (size_t)M * 4 * TD * 2;    // fc out / swiglu out
    u16* ab   = (u16*)ws;    ws += (size_t)M * 4 * TD * 2;    // h @ sw_W
    u16* bvb  = (u16*)ws;    ws += (size_t)M * 4 * TD * 2;    // h @ sw_V
    u16* xfb  = (u16*)ws;    ws += (size_t)TB * TD * 2;       // final-LN rows

    embed_k<<<M, 256, 0, stream>>>(idx, wte, wpe, x);

    for (int l = 0; l < 4; ++l) {
        const float* caw = c_attn_w + (size_t)l * 3 * TD * TD;
        const float* cab = c_attn_b + (size_t)l * 3 * TD;
        const float* cpw = c_proj_w + (size_t)l * TD * TD;
        const float* cpb = c_proj_b + (size_t)l * TD;
        const float* cfw = c_fc_w + (size_t)l * 4 * TD * TD;
        const float* cfb = c_fc_b + (size_t)l * 4 * TD;
        const float* swWl = sw_W + (size_t)l * 16 * TD * TD;
        const float* swVl = sw_V + (size_t)l * 16 * TD * TD;
        const float* swbl = sw_b + (size_t)l * 4 * TD;
        const float* swcl = sw_c + (size_t)l * 4 * TD;
        const float* mpw = mlp_proj_w + (size_t)l * 4 * TD * TD;
        const float* mpb = mlp_proj_b + (size_t)l * TD;

        ln_k<<<M, 256, 0, stream>>>(x, TD, ln1_w + l * TD, ln1_b + l * TD, xn);
        gemm_k<false, 0><<<dim3(3 * TD / BN, M / BM), 256, 0, stream>>>(
            xn, caw, cab, qkvb, nullptr, M, 3 * TD, TD);
        fattn_k<<<dim3(TB * TH, TT / 64), 256, 0, stream>>>(qkvb, yb);
        gemm_k<false, 1><<<dim3(TD / BN, M / BM), 256, 0, stream>>>(
            yb, cpw, cpb, nullptr, x, M, TD, TD);
        ln_k<<<M, 256, 0, stream>>>(x, TD, ln2_w + l * TD, ln2_b + l * TD, xn);
        gemm_k<false, 0><<<dim3(4 * TD / BN, M / BM), 256, 0, stream>>>(
            xn, cfw, cfb, hb, nullptr, M, 4 * TD, TD);
        gemm_k<true, 0><<<dim3(4 * TD / BN, M / BM), 256, 0, stream>>>(
            hb, swWl, swbl, ab, nullptr, M, 4 * TD, 4 * TD);
        gemm_k<true, 0><<<dim3(4 * TD / BN, M / BM), 256, 0, stream>>>(
            hb, swVl, swcl, bvb, nullptr, M, 4 * TD, 4 * TD);
        swiglu_k<<<(M * 4 * TD) / 256, 256, 0, stream>>>(ab, bvb, hb);
        gemm_k<false, 1><<<dim3(TD / BN, M / BM), 256, 0, stream>>>(
            hb, mpw, mpb, nullptr, x, M, TD, 4 * TD);
    }

    ln_k<<<TB, 256, 0, stream>>>(x + (size_t)(TT - 1) * TD, (size_t)TT * TD,
                                 lnf_w, lnf_b, xfb);
    lmhead_k<<<TV / 4, 256, 0, stream>>>(xfb, lm_head_w, out);
}